// Round 2
// baseline (804.622 us; speedup 1.0000x reference)
//
#include <hip/hip_runtime.h>

#define KSEG   1024
#define CCH    128
#define HWPIX  (512 * 512)
#define BB     4
#define BLOCK  256
#define W      8192                   // pixels per window
#define CGRP   32                     // channels per block
#define LITERS (W / (BLOCK * 4))      // 8 load iters (int4/float4 per thread)

// ord(-inf): 0xFF800000 ^ 0x7FFFFFFF
#define ORD_NEG_INF ((int)0x807FFFFF)

__device__ __forceinline__ int ord_f32(float f) {
    int i = __float_as_int(f);
    return i >= 0 ? i : (i ^ 0x7FFFFFFF);
}

__global__ __launch_bounds__(BLOCK) void init_kernel(int* __restrict__ out) {
    out[blockIdx.x * BLOCK + threadIdx.x] = ORD_NEG_INF;
}

__global__ __launch_bounds__(BLOCK) void decode_kernel(int* __restrict__ out) {
    const int idx = blockIdx.x * BLOCK + threadIdx.x;
    const int i = out[idx];
    ((float*)out)[idx] = __int_as_float(i >= 0 ? i : (i ^ 0x7FFFFFFF));
}

__global__ __launch_bounds__(BLOCK) void pool_kernel(const float* __restrict__ img,
                                                     const int* __restrict__ spx,
                                                     int* __restrict__ out) {
    __shared__ unsigned short sidx[W];        // 16 KiB: window pixels sorted by id
    __shared__ int start[KSEG + 1];           // 4 KiB: run offsets
    __shared__ int cursor[KSEG];              // 4 KiB: hist, then scatter cursors
    __shared__ __align__(16) float buf[W];    // 32 KiB: one channel of the window
    __shared__ int scanbuf[BLOCK];            // 1 KiB: block scan
    // total ~57.3 KiB -> 2 blocks/CU

    const int tid = threadIdx.x;
    const int b   = blockIdx.z;
    const int c0  = blockIdx.y * CGRP;
    const int wx  = blockIdx.x * W;
    const int* __restrict__ spx_w = spx + b * HWPIX + wx;
    const float* __restrict__ img_w = img + ((size_t)(b * CCH + c0)) * HWPIX + wx;

    // ---- Phase 1: counting sort of window pixel indices by segment id ----
    for (int i = tid; i < KSEG; i += BLOCK) cursor[i] = 0;
    __syncthreads();

    for (int it = 0; it < LITERS; ++it) {
        const int4 id = *(const int4*)(spx_w + (it * BLOCK + tid) * 4);
        atomicAdd(&cursor[id.x], 1);
        atomicAdd(&cursor[id.y], 1);
        atomicAdd(&cursor[id.z], 1);
        atomicAdd(&cursor[id.w], 1);
    }
    __syncthreads();

    // prefix sum over 1024 bins: thread t owns bins [4t, 4t+4)
    int loc[4], s0 = 0;
#pragma unroll
    for (int j = 0; j < 4; ++j) { loc[j] = s0; s0 += cursor[tid * 4 + j]; }
    scanbuf[tid] = s0;
    __syncthreads();
    for (int off = 1; off < BLOCK; off <<= 1) {
        const int v = (tid >= off) ? scanbuf[tid - off] : 0;
        __syncthreads();
        scanbuf[tid] += v;
        __syncthreads();
    }
    const int base = scanbuf[tid] - s0;       // exclusive prefix of thread totals
#pragma unroll
    for (int j = 0; j < 4; ++j) {
        start[tid * 4 + j]  = base + loc[j];
        cursor[tid * 4 + j] = base + loc[j];
    }
    if (tid == 0) start[KSEG] = W;
    __syncthreads();

    // scatter local pixel indices into sorted order
    for (int it = 0; it < LITERS; ++it) {
        const int p = (it * BLOCK + tid) * 4;
        const int4 id = *(const int4*)(spx_w + p);
        sidx[atomicAdd(&cursor[id.x], 1)] = (unsigned short)(p);
        sidx[atomicAdd(&cursor[id.y], 1)] = (unsigned short)(p + 1);
        sidx[atomicAdd(&cursor[id.z], 1)] = (unsigned short)(p + 2);
        sidx[atomicAdd(&cursor[id.w], 1)] = (unsigned short)(p + 3);
    }
    __syncthreads();

    // cache run bounds (invariant over channels)
    int rs[4], re[4];
#pragma unroll
    for (int q = 0; q < 4; ++q) {
        rs[q] = start[tid + q * BLOCK];
        re[q] = start[tid + q * BLOCK + 1];
    }

    const float NEG_INF = __int_as_float(0xFF800000);

    // ---- Phase 2: per channel, stage coalesced -> LDS, reduce runs ----
    float4 r[LITERS];
#pragma unroll
    for (int it = 0; it < LITERS; ++it)
        r[it] = *(const float4*)(img_w + (size_t)0 * HWPIX + (it * BLOCK + tid) * 4);

    for (int c = 0; c < CGRP; ++c) {
        __syncthreads();                      // buf free (previous gather done)
#pragma unroll
        for (int it = 0; it < LITERS; ++it)
            *(float4*)&buf[(it * BLOCK + tid) * 4] = r[it];
        if (c + 1 < CGRP) {
            const float* __restrict__ src = img_w + (size_t)(c + 1) * HWPIX;
#pragma unroll
            for (int it = 0; it < LITERS; ++it)
                r[it] = *(const float4*)(src + (it * BLOCK + tid) * 4);
        }
        __syncthreads();                      // buf ready

        int* __restrict__ outc = out + ((size_t)(b * CCH + c0 + c)) * KSEG;
#pragma unroll
        for (int q = 0; q < 4; ++q) {
            const int s = tid + q * BLOCK;
            float m = NEG_INF;
            int i = rs[q];
            const int e = re[q];
            for (; i + 4 <= e; i += 4) {      // 4-deep ILP to hide LDS latency
                const int i0 = sidx[i], i1 = sidx[i + 1], i2 = sidx[i + 2], i3 = sidx[i + 3];
                const float a = buf[i0], bb2 = buf[i1], cc = buf[i2], dd = buf[i3];
                m = fmaxf(m, fmaxf(fmaxf(a, bb2), fmaxf(cc, dd)));
            }
            for (; i < e; ++i) m = fmaxf(m, buf[sidx[i]]);
            atomicMax(&outc[s], ord_f32(m));  // empty run -> ORD_NEG_INF, no-op
        }
    }
}

extern "C" void kernel_launch(void* const* d_in, const int* in_sizes, int n_in,
                              void* d_out, int out_size, void* d_ws, size_t ws_size,
                              hipStream_t stream) {
    const float* img = (const float*)d_in[0];
    const int*   spx = (const int*)d_in[1];
    int* out = (int*)d_out;   // ordered-int during accumulation

    init_kernel<<<out_size / BLOCK, BLOCK, 0, stream>>>(out);

    dim3 grid(HWPIX / W, CCH / CGRP, BB);     // (32, 4, 4) = 512 blocks, 2/CU
    pool_kernel<<<grid, BLOCK, 0, stream>>>(img, spx, out);

    decode_kernel<<<out_size / BLOCK, BLOCK, 0, stream>>>(out);
}

// Round 3
// 731.633 us; speedup vs baseline: 1.0998x; 1.0998x over previous
//
#include <hip/hip_runtime.h>

#define KSEG   1024
#define CCH    128
#define HWPIX  (512 * 512)
#define BB     4
#define BLOCK  256
#define W      8192                   // pixels per window
#define CGRP   16                     // channels per block
#define PPT    (W / BLOCK)            // 32 pixels per thread
#define LITERS (W / (BLOCK * 4))      // 8 int4/float4 loads per thread

// ord(-inf): 0xFF800000 ^ 0x7FFFFFFF
#define ORD_NEG_INF ((int)0x807FFFFF)

__device__ __forceinline__ int ord_f32(float f) {
    int i = __float_as_int(f);
    return i >= 0 ? i : (i ^ 0x7FFFFFFF);
}

__global__ __launch_bounds__(BLOCK) void init_kernel(int* __restrict__ out) {
    out[blockIdx.x * BLOCK + threadIdx.x] = ORD_NEG_INF;
}

__global__ __launch_bounds__(BLOCK) void decode_kernel(int* __restrict__ out) {
    const int idx = blockIdx.x * BLOCK + threadIdx.x;
    const int i = out[idx];
    ((float*)out)[idx] = __int_as_float(i >= 0 ? i : (i ^ 0x7FFFFFFF));
}

__global__ __launch_bounds__(BLOCK) void pool_kernel(const float* __restrict__ img,
                                                     const int* __restrict__ spx,
                                                     int* __restrict__ out) {
    __shared__ __align__(16) float buf[W];    // 32 KiB: one channel, sorted order
    __shared__ int start[KSEG + 1];           // 4 KiB: run offsets (channel-invariant)
    __shared__ int cursor[KSEG];              // 4 KiB: hist, then scatter cursors
    __shared__ int scanbuf[BLOCK];            // 1 KiB
    // total ~41.3 KiB -> 3 blocks/CU, 12 waves/CU

    const int tid = threadIdx.x;
    const int b   = blockIdx.z;
    const int c0  = blockIdx.y * CGRP;
    const int wx  = blockIdx.x * W;
    const int* __restrict__ spx_w = spx + b * HWPIX + wx;
    const float* __restrict__ img_w = img + ((size_t)(b * CCH + c0)) * HWPIX + wx;

    // ---- Phase 1 (once per block): counting sort -> per-thread dest regs ----
    for (int i = tid; i < KSEG; i += BLOCK) cursor[i] = 0;
    __syncthreads();

    int4 ids[LITERS];
#pragma unroll
    for (int it = 0; it < LITERS; ++it) {
        ids[it] = *(const int4*)(spx_w + (it * BLOCK + tid) * 4);
        atomicAdd(&cursor[ids[it].x], 1);
        atomicAdd(&cursor[ids[it].y], 1);
        atomicAdd(&cursor[ids[it].z], 1);
        atomicAdd(&cursor[ids[it].w], 1);
    }
    __syncthreads();

    // prefix sum over 1024 bins: thread t owns bins [4t, 4t+4)
    int loc[4], s0 = 0;
#pragma unroll
    for (int j = 0; j < 4; ++j) { loc[j] = s0; s0 += cursor[tid * 4 + j]; }
    scanbuf[tid] = s0;
    __syncthreads();
    for (int off = 1; off < BLOCK; off <<= 1) {
        const int v = (tid >= off) ? scanbuf[tid - off] : 0;
        __syncthreads();
        scanbuf[tid] += v;
        __syncthreads();
    }
    const int base = scanbuf[tid] - s0;
#pragma unroll
    for (int j = 0; j < 4; ++j) {
        start[tid * 4 + j]  = base + loc[j];
        cursor[tid * 4 + j] = base + loc[j];
    }
    if (tid == 0) start[KSEG] = W;
    __syncthreads();

    // replay: destination slot of each of this thread's PPT pixels (channel-invariant)
    int dst[PPT];
#pragma unroll
    for (int it = 0; it < LITERS; ++it) {
        dst[it * 4 + 0] = atomicAdd(&cursor[ids[it].x], 1);
        dst[it * 4 + 1] = atomicAdd(&cursor[ids[it].y], 1);
        dst[it * 4 + 2] = atomicAdd(&cursor[ids[it].z], 1);
        dst[it * 4 + 3] = atomicAdd(&cursor[ids[it].w], 1);
    }

    // run bounds for the 4 segments this thread reduces (channel-invariant)
    int rs[4], re[4];
#pragma unroll
    for (int q = 0; q < 4; ++q) {
        rs[q] = start[tid + q * BLOCK];
        re[q] = start[tid + q * BLOCK + 1];
    }

    const float NEG_INF = __int_as_float(0xFF800000);

    // ---- Phase 2: per channel, scatter regs->sorted LDS, reduce contiguous runs ----
    float4 r[LITERS];
#pragma unroll
    for (int it = 0; it < LITERS; ++it)
        r[it] = *(const float4*)(img_w + (it * BLOCK + tid) * 4);

    for (int c = 0; c < CGRP; ++c) {
        __syncthreads();                      // buf free (previous reduce done)
#pragma unroll
        for (int it = 0; it < LITERS; ++it) {
            buf[dst[it * 4 + 0]] = r[it].x;
            buf[dst[it * 4 + 1]] = r[it].y;
            buf[dst[it * 4 + 2]] = r[it].z;
            buf[dst[it * 4 + 3]] = r[it].w;
        }
        if (c + 1 < CGRP) {
            const float* __restrict__ src = img_w + (size_t)(c + 1) * HWPIX;
#pragma unroll
            for (int it = 0; it < LITERS; ++it)
                r[it] = *(const float4*)(src + (it * BLOCK + tid) * 4);
        }
        __syncthreads();                      // buf ready

        int* __restrict__ outc = out + ((size_t)(b * CCH + c0 + c)) * KSEG;
#pragma unroll
        for (int q = 0; q < 4; ++q) {
            const int s = tid + q * BLOCK;
            int i = rs[q];
            const int e = re[q];
            float m = NEG_INF;
            if ((i & 1) && i < e) m = buf[i++];
            for (; i + 2 <= e; i += 2) {
                const float2 v = *(const float2*)&buf[i];
                m = fmaxf(m, fmaxf(v.x, v.y));
            }
            if (i < e) m = fmaxf(m, buf[i]);
            atomicMax(&outc[s], ord_f32(m));  // empty run -> no-op vs init
        }
    }
}

extern "C" void kernel_launch(void* const* d_in, const int* in_sizes, int n_in,
                              void* d_out, int out_size, void* d_ws, size_t ws_size,
                              hipStream_t stream) {
    const float* img = (const float*)d_in[0];
    const int*   spx = (const int*)d_in[1];
    int* out = (int*)d_out;   // ordered-int during accumulation

    init_kernel<<<out_size / BLOCK, BLOCK, 0, stream>>>(out);

    dim3 grid(HWPIX / W, CCH / CGRP, BB);     // (32, 8, 4) = 1024 blocks
    pool_kernel<<<grid, BLOCK, 0, stream>>>(img, spx, out);

    decode_kernel<<<out_size / BLOCK, BLOCK, 0, stream>>>(out);
}

// Round 4
// 727.855 us; speedup vs baseline: 1.1055x; 1.0052x over previous
//
#include <hip/hip_runtime.h>

#define KSEG   1024
#define CCH    128
#define HWPIX  (512 * 512)
#define BB     4
#define BLOCK  256
#define W      8192                   // pixels per window
#define CGRP   16                     // channels per block
#define PPT    (W / BLOCK)            // 32 pixels per thread
#define LITERS (W / (BLOCK * 4))      // 8 int4/float4 loads per thread

// ord(-inf): 0xFF800000 ^ 0x7FFFFFFF
#define ORD_NEG_INF ((int)0x807FFFFF)

__device__ __forceinline__ int ord_f32(float f) {
    int i = __float_as_int(f);
    return i >= 0 ? i : (i ^ 0x7FFFFFFF);
}

__global__ __launch_bounds__(BLOCK) void init_kernel(int* __restrict__ out) {
    out[blockIdx.x * BLOCK + threadIdx.x] = ORD_NEG_INF;
}

__global__ __launch_bounds__(BLOCK) void decode_kernel(int* __restrict__ out) {
    const int idx = blockIdx.x * BLOCK + threadIdx.x;
    const int i = out[idx];
    ((float*)out)[idx] = __int_as_float(i >= 0 ? i : (i ^ 0x7FFFFFFF));
}

__global__ __launch_bounds__(BLOCK) void pool_kernel(const float* __restrict__ img,
                                                     const int* __restrict__ spx,
                                                     int* __restrict__ out) {
    __shared__ __align__(16) float buf[W];    // 32 KiB: one channel, sorted order
    __shared__ int start[KSEG + 1];           // 4 KiB: run offsets (channel-invariant)
    __shared__ int cursor[KSEG];              // 4 KiB: hist, then scatter cursors
    __shared__ int scanbuf[BLOCK];            // 1 KiB
    // total ~41.3 KiB -> 3 blocks/CU, 12 waves/CU

    const int tid = threadIdx.x;
    const int b   = blockIdx.z;
    const int c0  = blockIdx.y * CGRP;
    const int wx  = blockIdx.x * W;
    const int* __restrict__ spx_w = spx + b * HWPIX + wx;
    const float* __restrict__ img_w = img + ((size_t)(b * CCH + c0)) * HWPIX + wx;

    // ---- Phase 1 (once per block): counting sort -> per-thread dest regs ----
    for (int i = tid; i < KSEG; i += BLOCK) cursor[i] = 0;
    __syncthreads();

    int4 ids[LITERS];
#pragma unroll
    for (int it = 0; it < LITERS; ++it) {
        ids[it] = *(const int4*)(spx_w + (it * BLOCK + tid) * 4);
        atomicAdd(&cursor[ids[it].x], 1);
        atomicAdd(&cursor[ids[it].y], 1);
        atomicAdd(&cursor[ids[it].z], 1);
        atomicAdd(&cursor[ids[it].w], 1);
    }
    __syncthreads();

    // prefix sum over 1024 bins: thread t owns bins [4t, 4t+4)
    int loc[4], s0 = 0;
#pragma unroll
    for (int j = 0; j < 4; ++j) { loc[j] = s0; s0 += cursor[tid * 4 + j]; }
    scanbuf[tid] = s0;
    __syncthreads();
    for (int off = 1; off < BLOCK; off <<= 1) {
        const int v = (tid >= off) ? scanbuf[tid - off] : 0;
        __syncthreads();
        scanbuf[tid] += v;
        __syncthreads();
    }
    const int base = scanbuf[tid] - s0;
#pragma unroll
    for (int j = 0; j < 4; ++j) {
        start[tid * 4 + j]  = base + loc[j];
        cursor[tid * 4 + j] = base + loc[j];
    }
    if (tid == 0) start[KSEG] = W;
    __syncthreads();

    // replay: destination slot of each of this thread's PPT pixels (channel-invariant)
    int dst[PPT];
#pragma unroll
    for (int it = 0; it < LITERS; ++it) {
        dst[it * 4 + 0] = atomicAdd(&cursor[ids[it].x], 1);
        dst[it * 4 + 1] = atomicAdd(&cursor[ids[it].y], 1);
        dst[it * 4 + 2] = atomicAdd(&cursor[ids[it].z], 1);
        dst[it * 4 + 3] = atomicAdd(&cursor[ids[it].w], 1);
    }

    // run bounds for the 4 segments this thread reduces (channel-invariant)
    int rs[4], re[4];
#pragma unroll
    for (int q = 0; q < 4; ++q) {
        rs[q] = start[tid + q * BLOCK];
        re[q] = start[tid + q * BLOCK + 1];
    }

    const float NEG_INF = __int_as_float(0xFF800000);

    // ---- Phase 2: per channel, scatter regs->sorted LDS, reduce contiguous runs.
    // Prefetch for c+1 is issued AFTER the "buf ready" barrier so the barrier's
    // vmcnt(0) drain does NOT serialize on it; loads overlap the reduce. ----
    float4 r[LITERS];
#pragma unroll
    for (int it = 0; it < LITERS; ++it)
        r[it] = *(const float4*)(img_w + (it * BLOCK + tid) * 4);

    for (int c = 0; c < CGRP; ++c) {
        __syncthreads();                      // buf free (previous reduce done; r[] drained)
#pragma unroll
        for (int it = 0; it < LITERS; ++it) {
            buf[dst[it * 4 + 0]] = r[it].x;
            buf[dst[it * 4 + 1]] = r[it].y;
            buf[dst[it * 4 + 2]] = r[it].z;
            buf[dst[it * 4 + 3]] = r[it].w;
        }
        __syncthreads();                      // buf ready (lgkm drain only matters here)

        if (c + 1 < CGRP) {                   // issue next-channel loads NOW; they fly
            const float* __restrict__ src = img_w + (size_t)(c + 1) * HWPIX;
#pragma unroll
            for (int it = 0; it < LITERS; ++it)
                r[it] = *(const float4*)(src + (it * BLOCK + tid) * 4);
        }

        int* __restrict__ outc = out + ((size_t)(b * CCH + c0 + c)) * KSEG;
#pragma unroll
        for (int q = 0; q < 4; ++q) {
            const int s = tid + q * BLOCK;
            int i = rs[q];
            const int e = re[q];
            float m = NEG_INF;
            if ((i & 1) && i < e) m = buf[i++];
            for (; i + 2 <= e; i += 2) {
                const float2 v = *(const float2*)&buf[i];
                m = fmaxf(m, fmaxf(v.x, v.y));
            }
            if (i < e) m = fmaxf(m, buf[i]);
            atomicMax(&outc[s], ord_f32(m));  // empty run -> no-op vs init
        }
    }
}

extern "C" void kernel_launch(void* const* d_in, const int* in_sizes, int n_in,
                              void* d_out, int out_size, void* d_ws, size_t ws_size,
                              hipStream_t stream) {
    const float* img = (const float*)d_in[0];
    const int*   spx = (const int*)d_in[1];
    int* out = (int*)d_out;   // ordered-int during accumulation

    init_kernel<<<out_size / BLOCK, BLOCK, 0, stream>>>(out);

    dim3 grid(HWPIX / W, CCH / CGRP, BB);     // (32, 8, 4) = 1024 blocks
    pool_kernel<<<grid, BLOCK, 0, stream>>>(img, spx, out);

    decode_kernel<<<out_size / BLOCK, BLOCK, 0, stream>>>(out);
}